// Round 4
// baseline (385.276 us; speedup 1.0000x reference)
//
#include <hip/hip_runtime.h>

#define TT 512
#define BB 256
#define NN 128

// Fully fused CRF NLL kernel. One workgroup (4 waves) per batch chain.
//
// Forward recursion in linear space: state W[j] = exp(u[j] - Lambda) in LDS
// (double-buffered, 4 chunks of 32 floats padded to 36 for conflict-free
// 4-address b128 reads). Decomposition: wave w owns j in [32w,32w+32);
// lane l = 16*q + i handles j0 = 32w+2i (+1) with K-quarter q -> each lane
// reads only 32 floats (8 ds_read_b128 per wave per step). Partials combined
// with shfl_xor(16/32) butterflies (no LDS round-trip). One barrier per step.
// Normalizer = W[0] of the input state via readfirstlane (rcp error cancels
// exactly: Lambda tracks log of the *stored* state).
__global__ __launch_bounds__(256, 1) void crf_fused(
    const float* __restrict__ emit, const int* __restrict__ target,
    const void* __restrict__ maskp, const float* __restrict__ trans,
    const float* __restrict__ strans, const float* __restrict__ etrans,
    float* __restrict__ ws, float* __restrict__ out) {
  __shared__ __align__(16) float sW[2][144];  // [buf][36*q + (j&31)]
  __shared__ float sh_f[4];
  __shared__ int sh_i[4];
  __shared__ float sh_u00;
  __shared__ int sh_len;

  const int tid = threadIdx.x;
  const int b = blockIdx.x;
  const int w = tid >> 6;
  const int l = tid & 63;
  const int q = l >> 4;
  const int i = l & 15;
  const int j0 = 32 * w + 2 * i;

  const unsigned char* mk8 = (const unsigned char*)maskp;
  const int* mk32 = (const int*)maskp;
  const bool is_u8 = (mk8[1] != 0);

  // ---- fused pass: sequence length + gold-path score ----
  int cnt = 0;
  float sc = 0.f;
#pragma unroll
  for (int r = 0; r < 2; ++r) {
    int t = tid + 256 * r;
    int m = is_u8 ? (mk8[t * BB + b] != 0) : (mk32[t * BB + b] != 0);
    cnt += m;
    if (m) {
      int tg = target[t * BB + b];
      float v = emit[((size_t)t * BB + b) * NN + tg];
      v += (t > 0) ? trans[target[(t - 1) * BB + b] * NN + tg] : strans[tg];
      int mn = (t + 1 < TT)
                   ? (is_u8 ? (mk8[(t + 1) * BB + b] != 0)
                            : (mk32[(t + 1) * BB + b] != 0))
                   : 0;
      if (!mn) v += etrans[tg];  // prefix mask edge = last valid step
      sc += v;
    }
  }
#pragma unroll
  for (int off = 32; off; off >>= 1) {
    cnt += __shfl_down(cnt, off, 64);
    sc += __shfl_down(sc, off, 64);
  }
  if (l == 0) {
    sh_i[w] = cnt;
    sh_f[w] = sc;
  }
  __syncthreads();
  if (tid == 0) {
    sh_len = sh_i[0] + sh_i[1] + sh_i[2] + sh_i[3];
    atomicAdd(&ws[1], sh_f[0] + sh_f[1] + sh_f[2] + sh_f[3]);
  }

  // ---- E = exp(trans) registers: e0[k]=E[32q+k][j0], e1[k]=E[32q+k][j0+1] ----
  float e0[32], e1[32];
#pragma unroll
  for (int k = 0; k < 32; ++k) {
    e0[k] = __expf(trans[(32 * q + k) * NN + j0]);
    e1[k] = __expf(trans[(32 * q + k) * NN + j0 + 1]);
  }

  // ---- init state W_0[j] = exp(u0[j] - u0[0]) in buf 0 ----
  float u0 = 0.f;
  if (tid < NN) u0 = strans[tid] + emit[(size_t)b * NN + tid];
  if (tid == 0) sh_u00 = u0;
  __syncthreads();
  const int len = sh_len;
  const float u00 = sh_u00;
  float L = 0.f;
  if (tid == 0) L = u00;
  if (tid < NN) sW[0][36 * (tid >> 5) + (tid & 31)] = __expf(u0 - u00);

  // ---- emit prefetch (as exp) for steps t = 1..8 ----
  float2 xb[8];
#pragma unroll
  for (int k = 0; k < 8; ++k) {
    int t = 1 + k;
    float2 ev = (t < TT)
                    ? *(const float2*)&emit[((size_t)t * BB + b) * NN + j0]
                    : make_float2(0.f, 0.f);
    xb[k] = make_float2(__expf(ev.x), __expf(ev.y));
  }
  __syncthreads();

  const int total = len - 1;  // steps t = 1..len-1
  const int G = total >> 3;
  const int rem = total & 7;

#define CRF_STEP(PIN, POUT, XK)                                              \
  do {                                                                       \
    const float4* p4 = reinterpret_cast<const float4*>(&sW[PIN][0]) + 9 * q; \
    float4 vv[8];                                                            \
    _Pragma("unroll") for (int c = 0; c < 8; ++c) vv[c] = p4[c];             \
    const float w00 = __uint_as_float(                                       \
        __builtin_amdgcn_readfirstlane(__float_as_uint(vv[0].x)));           \
    float a0 = 0.f, b0 = 0.f, a1 = 0.f, b1 = 0.f;                            \
    _Pragma("unroll") for (int c = 0; c < 8; c += 2) {                       \
      a0 = fmaf(vv[c].x, e0[4 * c + 0], a0);                                 \
      a0 = fmaf(vv[c].y, e0[4 * c + 1], a0);                                 \
      a0 = fmaf(vv[c].z, e0[4 * c + 2], a0);                                 \
      a0 = fmaf(vv[c].w, e0[4 * c + 3], a0);                                 \
      a1 = fmaf(vv[c].x, e1[4 * c + 0], a1);                                 \
      a1 = fmaf(vv[c].y, e1[4 * c + 1], a1);                                 \
      a1 = fmaf(vv[c].z, e1[4 * c + 2], a1);                                 \
      a1 = fmaf(vv[c].w, e1[4 * c + 3], a1);                                 \
      b0 = fmaf(vv[c + 1].x, e0[4 * c + 4], b0);                             \
      b0 = fmaf(vv[c + 1].y, e0[4 * c + 5], b0);                             \
      b0 = fmaf(vv[c + 1].z, e0[4 * c + 6], b0);                             \
      b0 = fmaf(vv[c + 1].w, e0[4 * c + 7], b0);                             \
      b1 = fmaf(vv[c + 1].x, e1[4 * c + 4], b1);                             \
      b1 = fmaf(vv[c + 1].y, e1[4 * c + 5], b1);                             \
      b1 = fmaf(vv[c + 1].z, e1[4 * c + 6], b1);                             \
      b1 = fmaf(vv[c + 1].w, e1[4 * c + 7], b1);                             \
    }                                                                        \
    float s0 = a0 + b0, s1 = a1 + b1;                                        \
    s0 += __shfl_xor(s0, 16, 64);                                            \
    s0 += __shfl_xor(s0, 32, 64);                                            \
    s1 += __shfl_xor(s1, 16, 64);                                            \
    s1 += __shfl_xor(s1, 32, 64);                                            \
    const float fr = __builtin_amdgcn_rcpf(w00);                             \
    L += __logf(w00);                                                        \
    if (q == 0)                                                              \
      *((float2*)&sW[POUT][36 * w] + i) =                                    \
          make_float2(s0 * (XK).x * fr, s1 * (XK).y * fr);                   \
    __syncthreads();                                                         \
  } while (0)

  for (int g = 0; g < G; ++g) {
    const int tb = 1 + 8 * g;
    // prefetch next group's emit rows
    float2 en[8];
#pragma unroll
    for (int k = 0; k < 8; ++k) {
      int t = tb + 8 + k;
      en[k] = (t < TT)
                  ? *(const float2*)&emit[((size_t)t * BB + b) * NN + j0]
                  : make_float2(0.f, 0.f);
    }
#pragma unroll
    for (int k = 0; k < 8; ++k) {
      CRF_STEP((k & 1), ((k + 1) & 1), xb[k]);
    }
#pragma unroll
    for (int k = 0; k < 8; ++k)
      xb[k] = make_float2(__expf(en[k].x), __expf(en[k].y));
  }
  // tail: remaining rem (< 8) steps, same parity sequence (8G is even)
#pragma unroll
  for (int k = 0; k < 7; ++k) {
    if (k >= rem) break;
    CRF_STEP((k & 1), ((k + 1) & 1), xb[k]);
  }

  // ---- final: logZ_b = L + log(sum_j W_final[j] * exp(etrans[j])) ----
  const int pf = total & 1;
  float y = 0.f;
  if (tid < NN)
    y = sW[pf][36 * (tid >> 5) + (tid & 31)] * __expf(etrans[tid]);
#pragma unroll
  for (int off = 32; off; off >>= 1) y += __shfl_down(y, off, 64);
  if (l == 0) sh_f[w] = y;
  __syncthreads();
  if (tid == 0) {
    atomicAdd(&ws[0], L + __logf(sh_f[0] + sh_f[1]));
    __threadfence();
    unsigned old = atomicAdd((unsigned*)ws + 2, 1u);
    if (old == BB - 1) {  // last block to finish computes the output
      float zz = atomicAdd(&ws[0], 0.f);
      float ss = atomicAdd(&ws[1], 0.f);
      out[0] = (zz - ss) * (1.0f / (float)BB);
    }
  }
#undef CRF_STEP
}

extern "C" void kernel_launch(void* const* d_in, const int* in_sizes, int n_in,
                              void* d_out, int out_size, void* d_ws, size_t ws_size,
                              hipStream_t stream) {
  const float* emit = (const float*)d_in[0];
  const int* target = (const int*)d_in[1];
  const void* mask = (const void*)d_in[2];
  const float* trans = (const float*)d_in[3];
  const float* strans = (const float*)d_in[4];
  const float* etrans = (const float*)d_in[5];
  float* ws = (float*)d_ws;
  float* out = (float*)d_out;

  hipMemsetAsync(d_ws, 0, 16, stream);
  crf_fused<<<BB, 256, 0, stream>>>(emit, target, mask, trans, strans, etrans,
                                    ws, out);
}